// Round 3
// baseline (403.342 us; speedup 1.0000x reference)
//
#include <hip/hip_runtime.h>

#define NB 1000000
#define NA 40
#define THREADS 256
#define SPT 4                                   // samples per thread
#define NTHREADS (NB / SPT)                     // 250000 (NB divisible by 4)
#define NBLOCKS ((NTHREADS + THREADS - 1) / THREADS)  // 977
#define NEG_LN2_OVER_A (-0.017328679513998632f) // -ln(2)/40

// Round-3 structure: LDS-free, barrier-free. Each thread owns 4 consecutive
// samples, so the [A,B] target layout transposes in-register:
//   int4  targets[a][4g..4g+3]  = my 4 labels at attr a   (wave-coalesced 16B)
//   float4 inputs[s][4c..4c+3]  = 4 attrs of my sample s  (per-lane sequential)
// 10 independent attr-chunks, fully unrolled -> compiler pipelines loads with
// no vmcnt(0) drain (rounds 1-2 were latency-bound on the LDS barrier drain).
__global__ __launch_bounds__(THREADS) void focal_loss_kernel(
    const float* __restrict__ inputs,    // [NB, NA] f32
    const int*   __restrict__ targets,   // [NA, NB] i32 in {0,1}
    const float* __restrict__ attr_w,    // [NA] f32
    float* __restrict__ out)             // [1] f32 (pre-zeroed)
{
    __shared__ float s_red[THREADS / 64];
    const int gid = blockIdx.x * THREADS + threadIdx.x;

    float acc0 = 0.0f, acc1 = 0.0f, acc2 = 0.0f, acc3 = 0.0f;

    if (gid < NTHREADS) {
        const size_t s0  = (size_t)gid * SPT;
        const float* inp = inputs + s0 * NA;

// elem(s,k): x = xv{s} comp k, label = tv{k} comp s, weight = aw comp k
#define ELEM(X, LBL, AWK, ACC) {                      \
        const float x_  = (X);                        \
        const float om_ = 1.0f - x_;                  \
        const float w_  = (AWK) * (om_ * om_);        \
        const float p_  = fmaxf(x_,  1e-12f);         \
        const float q_  = fmaxf(om_, 1e-12f);         \
        ACC = fmaf(w_, __log2f((LBL) ? p_ : q_), ACC); }

        #pragma unroll
        for (int c = 0; c < NA / 4; ++c) {
            const int4 tv0 = *(const int4*)(targets + (size_t)(4 * c + 0) * NB + s0);
            const int4 tv1 = *(const int4*)(targets + (size_t)(4 * c + 1) * NB + s0);
            const int4 tv2 = *(const int4*)(targets + (size_t)(4 * c + 2) * NB + s0);
            const int4 tv3 = *(const int4*)(targets + (size_t)(4 * c + 3) * NB + s0);
            const float4 xv0 = *(const float4*)(inp + 0 * NA + 4 * c);
            const float4 xv1 = *(const float4*)(inp + 1 * NA + 4 * c);
            const float4 xv2 = *(const float4*)(inp + 2 * NA + 4 * c);
            const float4 xv3 = *(const float4*)(inp + 3 * NA + 4 * c);
            const float4 aw  = *(const float4*)(attr_w + 4 * c);

            ELEM(xv0.x, tv0.x, aw.x, acc0) ELEM(xv0.y, tv1.x, aw.y, acc0)
            ELEM(xv0.z, tv2.x, aw.z, acc0) ELEM(xv0.w, tv3.x, aw.w, acc0)
            ELEM(xv1.x, tv0.y, aw.x, acc1) ELEM(xv1.y, tv1.y, aw.y, acc1)
            ELEM(xv1.z, tv2.y, aw.z, acc1) ELEM(xv1.w, tv3.y, aw.w, acc1)
            ELEM(xv2.x, tv0.z, aw.x, acc2) ELEM(xv2.y, tv1.z, aw.y, acc2)
            ELEM(xv2.z, tv2.z, aw.z, acc2) ELEM(xv2.w, tv3.z, aw.w, acc2)
            ELEM(xv3.x, tv0.w, aw.x, acc3) ELEM(xv3.y, tv1.w, aw.y, acc3)
            ELEM(xv3.z, tv2.w, aw.z, acc3) ELEM(xv3.w, tv3.w, aw.w, acc3)
        }
#undef ELEM
    }

    // fold -ln2/40 once; then 64-lane shuffle -> cross-wave LDS -> one atomic
    float v = ((acc0 + acc1) + (acc2 + acc3)) * NEG_LN2_OVER_A;
    #pragma unroll
    for (int off = 32; off > 0; off >>= 1)
        v += __shfl_xor(v, off, 64);
    const int t = threadIdx.x;
    if ((t & 63) == 0) s_red[t >> 6] = v;
    __syncthreads();
    if (t == 0) {
        float r2 = 0.0f;
        #pragma unroll
        for (int w2 = 0; w2 < THREADS / 64; ++w2) r2 += s_red[w2];
        atomicAdd(out, r2);
    }
}

extern "C" void kernel_launch(void* const* d_in, const int* in_sizes, int n_in,
                              void* d_out, int out_size, void* d_ws, size_t ws_size,
                              hipStream_t stream) {
    const float* inputs  = (const float*)d_in[0];
    const int*   targets = (const int*)d_in[1];
    const float* attr_w  = (const float*)d_in[2];
    float* out = (float*)d_out;
    hipMemsetAsync(out, 0, sizeof(float), stream);
    focal_loss_kernel<<<dim3(NBLOCKS), dim3(THREADS), 0, stream>>>(inputs, targets, attr_w, out);
}

// Round 4
// 325.669 us; speedup vs baseline: 1.2385x; 1.2385x over previous
//
#include <hip/hip_runtime.h>

#define NB 1000000
#define NA 40
#define THREADS 256
#define WPB (THREADS / 64)                      // waves per block
#define NBLOCKS 977
#define NCHUNKS (NB / 64)                       // 15625, exact (no tail)
#define NEG_LN2_OVER_A (-0.017328679513998632f) // -ln(2)/40

// Round-4: barrier-free, LDS-free (except 16B final reduce), both streams
// wave-coalesced. Wave owns 64 consecutive samples/chunk:
//   labels: 40 coalesced dword loads -> lane i holds sample s0+i's 40 labels,
//           packed to a 40-bit word (in-register transpose, no LDS)
//   inputs: 10 coalesced float4 loads; label word for float4 j fetched from
//           lane (lane+64j)/10 via __shfl (intra-wave, no barrier)
// Round-3 lesson: per-lane-sequential reads over-fetched 2.7x (591MB) via
// L1/L2 thrash; round-2 lesson: LDS barrier drain serialized tiny blocks.
__global__ __launch_bounds__(THREADS) void focal_loss_kernel(
    const float* __restrict__ inputs,    // [NB, NA] f32
    const int*   __restrict__ targets,   // [NA, NB] i32 in {0,1}
    const float* __restrict__ attr_w,    // [NA] f32
    float* __restrict__ out)             // [1] f32 (pre-zeroed)
{
    __shared__ float s_red[WPB];
    const int lane = threadIdx.x & 63;
    const int wid  = blockIdx.x * WPB + (threadIdx.x >> 6);
    const int W    = NBLOCKS * WPB;

    // lane-constant slot tables; slots j and j+5 share c(+32), r, weights
    int cj[5], rj[5];
    float4 wt[5];
    #pragma unroll
    for (int j = 0; j < 5; ++j) {
        const int f = lane + 64 * j;
        cj[j] = f / 10;
        rj[j] = 4 * (f - 10 * cj[j]);            // attr base 0,4,...,36
        wt[j] = *(const float4*)(attr_w + rj[j]); // 16B-aligned (rj%4==0)
    }

    float acc = 0.0f;

    for (int ch = wid; ch < NCHUNKS; ch += W) {
        const int s0 = ch * 64;

        // ---- batched coalesced loads: 40 label dwords + 10 input float4 ----
        int lab[NA];
        #pragma unroll
        for (int a = 0; a < NA; ++a)
            lab[a] = targets[(size_t)a * NB + (s0 + lane)];

        const float4* in4 = (const float4*)inputs + (size_t)s0 * 10;
        float4 xv[10];
        #pragma unroll
        for (int j = 0; j < 10; ++j)
            xv[j] = in4[lane + 64 * j];

        // ---- in-register transpose: my sample's 40-bit label word ----
        unsigned wlo = 0u, whi = 0u;
        #pragma unroll
        for (int a = 0; a < 32; ++a) wlo |= (unsigned)(lab[a] & 1) << a;
        #pragma unroll
        for (int a = 32; a < NA; ++a) whi |= (unsigned)(lab[a] & 1) << (a - 32);

        // ---- compute: fetch word of my float4's sample via shfl ----
#define ELEM(X, BIT, AWK) {                                   \
            const float x_  = (X);                            \
            const float om_ = 1.0f - x_;                      \
            const float w_  = (AWK) * (om_ * om_);            \
            const float p_  = fmaxf(x_,  1e-12f);             \
            const float q_  = fmaxf(om_, 1e-12f);             \
            acc = fmaf(w_, __log2f((BIT) ? p_ : q_), acc); }

        #pragma unroll
        for (int j = 0; j < 10; ++j) {
            const int jj = (j < 5) ? j : j - 5;
            const int cs = cj[jj] + ((j < 5) ? 0 : 32);       // source lane
            const unsigned lo = (unsigned)__shfl((int)wlo, cs, 64);
            const unsigned hi = (unsigned)__shfl((int)whi, cs, 64);
            const int r = rj[jj];
            const unsigned nib = ((r < 32) ? (lo >> r) : (hi >> (r - 32))) & 15u;
            const float4 x4 = xv[j];
            const float4 w4 = wt[jj];
            ELEM(x4.x, nib & 1u, w4.x)
            ELEM(x4.y, nib & 2u, w4.y)
            ELEM(x4.z, nib & 4u, w4.z)
            ELEM(x4.w, nib & 8u, w4.w)
        }
#undef ELEM
    }

    // ---- reduce: 64-lane shuffle -> cross-wave LDS -> one atomic/block ----
    float v = acc * NEG_LN2_OVER_A;
    #pragma unroll
    for (int off = 32; off > 0; off >>= 1)
        v += __shfl_xor(v, off, 64);
    const int t = threadIdx.x;
    if ((t & 63) == 0) s_red[t >> 6] = v;
    __syncthreads();
    if (t == 0) {
        float r2 = 0.0f;
        #pragma unroll
        for (int w2 = 0; w2 < WPB; ++w2) r2 += s_red[w2];
        atomicAdd(out, r2);
    }
}

extern "C" void kernel_launch(void* const* d_in, const int* in_sizes, int n_in,
                              void* d_out, int out_size, void* d_ws, size_t ws_size,
                              hipStream_t stream) {
    const float* inputs  = (const float*)d_in[0];
    const int*   targets = (const int*)d_in[1];
    const float* attr_w  = (const float*)d_in[2];
    float* out = (float*)d_out;
    hipMemsetAsync(out, 0, sizeof(float), stream);
    focal_loss_kernel<<<dim3(NBLOCKS), dim3(THREADS), 0, stream>>>(inputs, targets, attr_w, out);
}